// Round 3
// baseline (896.543 us; speedup 1.0000x reference)
//
#include <hip/hip_runtime.h>
#include <hip/hip_bf16.h>

typedef __attribute__((ext_vector_type(8))) short short8;
typedef __attribute__((ext_vector_type(4))) short short4_t;
typedef __attribute__((ext_vector_type(4))) float float4_t;
typedef unsigned short ushort;

#define HW 4096
#define CC 256
#define NBATCH 4

#define GLDS(g, l) __builtin_amdgcn_global_load_lds( \
    (const __attribute__((address_space(1))) void*)(g), \
    (__attribute__((address_space(3))) void*)(l), 16, 0, 0)

static __device__ __forceinline__ unsigned short f2b(float f) {
    union { float f; unsigned u; } v; v.f = f;
    unsigned r = v.u + 0x7FFF + ((v.u >> 16) & 1);   // RNE
    return (unsigned short)(r >> 16);
}

// ---- kernel 1: x[n][c][p] -> XT[n][p][c] (bf16) and gb[n][c][p] (bf16),
//      with fused fp32->bf16 weight conversion (first 768 flat blocks). ----
__global__ __launch_bounds__(256) void k_prep(const float* __restrict__ x,
                                              const float* __restrict__ tw,
                                              const float* __restrict__ pw,
                                              const float* __restrict__ cw,
                                              unsigned short* __restrict__ XT,
                                              unsigned short* __restrict__ gb,
                                              unsigned short* __restrict__ Wbt,
                                              unsigned short* __restrict__ Wbp,
                                              unsigned short* __restrict__ Wbc) {
    __shared__ float T[64][65];
    int fb = blockIdx.x + 64 * (blockIdx.y + 4 * blockIdx.z);
    if (fb < 768) {            // 768*256 = 196608 = 3 x 256x256 weights
        int i = fb * 256 + threadIdx.x;
        int sel = i >> 16, off = i & 65535;
        const float* s = sel == 0 ? tw : (sel == 1 ? pw : cw);
        unsigned short* d = sel == 0 ? Wbt : (sel == 1 ? Wbp : Wbc);
        d[off] = f2b(s[off]);
    }
    int n = blockIdx.z, c0 = blockIdx.y * 64, p0 = blockIdx.x * 64;
    int t = threadIdx.x;
    int pl = t & 63, rg = t >> 6;
    const float* xp = x + ((size_t)n * CC + c0) * HW + p0;
    #pragma unroll
    for (int i = 0; i < 16; i++) {
        int cl = rg * 16 + i;
        float v = xp[(size_t)cl * HW + pl];
        T[cl][pl] = v;
        gb[((size_t)n * CC + c0 + cl) * HW + p0 + pl] = f2b(v);
    }
    __syncthreads();
    int cl = t & 63, pg = t >> 6;
    unsigned short* xt = XT + ((size_t)n * HW + p0) * CC + c0;
    #pragma unroll
    for (int i = 0; i < 16; i++) {
        int plw = pg * 16 + i;
        xt[(size_t)plw * CC + cl] = f2b(T[cl][plw]);
    }
}

// ---- kernel 2: projection GEMM  outT[p][co] = sum_ci XT[p][ci]*W[co][ci] + b[co] ----
__global__ __launch_bounds__(256) void k_proj(const unsigned short* __restrict__ XT,
                                              const unsigned short* __restrict__ Wt,
                                              const unsigned short* __restrict__ Wp,
                                              const float* __restrict__ bt,
                                              const float* __restrict__ bp,
                                              unsigned short* __restrict__ outT_t,
                                              unsigned short* __restrict__ outT_p) {
    const unsigned short* W; const float* b; unsigned short* outT;
    if (blockIdx.y == 0) { W = Wt; b = bt; outT = outT_t; }
    else                 { W = Wp; b = bp; outT = outT_p; }
    int w = threadIdx.x >> 6, lane = threadIdx.x & 63;
    int nidx = lane & 15, quad = lane >> 4;
    size_t row0 = (size_t)blockIdx.x * 64 + w * 16;
    float4_t acc[16];
    #pragma unroll
    for (int i = 0; i < 16; i++) acc[i] = (float4_t)(0.f);
    const unsigned short* arow = XT + (row0 + nidx) * CC + quad * 8;
    for (int ks = 0; ks < 8; ks++) {
        short8 a = *(const short8*)(arow + ks * 32);
        #pragma unroll
        for (int cb = 0; cb < 16; cb++) {
            short8 bb = *(const short8*)(W + (size_t)(cb * 16 + nidx) * CC + ks * 32 + quad * 8);
            acc[cb] = __builtin_amdgcn_mfma_f32_16x16x32_bf16(a, bb, acc[cb], 0, 0, 0);
        }
    }
    #pragma unroll
    for (int cb = 0; cb < 16; cb++) {
        int co = cb * 16 + nidx;
        float bias = b[co];
        #pragma unroll
        for (int r = 0; r < 4; r++) {
            size_t prow = row0 + quad * 4 + r;
            outT[prow * CC + co] = f2b(acc[cb][r] + bias);
        }
    }
}

// ---- kernel 3: flash attention, no-max softmax, zero-replication LDS.
// Block = 64 queries, 4 waves. Key tile = 64, 64 iterations.
// QK^T: wave w owns keys [w*16, w*16+16) of each tile; K-frags prefetched
//   from global straight into ping-pong registers (no K LDS). theta in regs.
// PV: wave w owns channels [w*64, w*64+64); A = V-frags (own slice only),
//   B = P-frags (8 KB, via LDS). Row sums l via ones-MFMA on P-frags.
__global__ __launch_bounds__(256, 1) void k_attn(const unsigned short* __restrict__ thetaT,
                                                 const unsigned short* __restrict__ phiT,
                                                 const unsigned short* __restrict__ gb,
                                                 unsigned short* __restrict__ fT) {
    __shared__ __align__(16) ushort Vbuf[2][2][256][32];  // [buf][khalf][ch][key] 64 KB
    __shared__ __align__(16) ushort Pbuf[64][72];         // [q][key] stride 72 -> balanced
    __shared__ float Lbuf[64];

    const int tid = threadIdx.x;
    const int w = tid >> 6, lane = tid & 63;
    const int nidx = lane & 15, quad = lane >> 4;
    const int nb = (blockIdx.x & 7) >> 1;
    const int tile = ((blockIdx.x >> 3) << 1) | (blockIdx.x & 1);
    const int p0 = tile * 64;
    const size_t seq0 = (size_t)nb * HW;
    const ushort* Kg = phiT + seq0 * CC;                  // [4096][256]
    const ushort* Vg = gb + (size_t)nb * CC * HW;         // [256][4096]

    // theta A-frags for all 64 queries of this block (128 VGPR)
    short8 aq[4][8];
    #pragma unroll
    for (int qt = 0; qt < 4; qt++) {
        const ushort* qrow = thetaT + (seq0 + p0 + qt * 16 + nidx) * CC + quad * 8;
        #pragma unroll
        for (int kb = 0; kb < 8; kb++) aq[qt][kb] = *(const short8*)(qrow + kb * 32);
    }

    float4_t o[4][4];
    #pragma unroll
    for (int i = 0; i < 4; i++)
        #pragma unroll
        for (int j = 0; j < 4; j++) o[i][j] = (float4_t)(0.f);
    float4_t lacc = (float4_t)(0.f);
    const short8 ones8 = {0x3F80, 0x3F80, 0x3F80, 0x3F80, 0x3F80, 0x3F80, 0x3F80, 0x3F80};

    // V staging: wave w -> khalf = w>>1, channels (w&1)*128 + j*16 .. (+16)
    const int s_kh = w >> 1;
    const int s_ch0 = (w & 1) * 128;
    const int s_chl = lane >> 2;
    const int s_kc = (lane & 3) * 8;

    // K-frag global pointer: row = key (w*16+nidx), col = quad*8 (+kb*32, +t*64 rows)
    const ushort* kfp = Kg + (size_t)(w * 16 + nidx) * CC + quad * 8;

    short8 kr[2][8];
    // prologue: prefetch tile 0
    #pragma unroll
    for (int kb = 0; kb < 8; kb++) kr[0][kb] = *(const short8*)(kfp + kb * 32);
    #pragma unroll
    for (int j = 0; j < 8; j++) {
        int ch = s_ch0 + j * 16 + s_chl;
        GLDS(Vg + (size_t)ch * HW + s_kh * 32 + s_kc, &Vbuf[0][s_kh][s_ch0 + j * 16][0]);
    }

    const float SC = 0.0625f * 1.44269504088896f;         // /sqrt(256) * log2(e)
    #pragma unroll 2
    for (int t = 0; t < 64; t++) {
        const int vb = t & 1;
        asm volatile("s_waitcnt vmcnt(0)" ::: "memory");  // K-frags(t) + V-DMA(t) landed
        __syncthreads();                                  // B1: V(t) visible to all waves
        if (t < 63) {                                     // prefetch t+1 (overlaps compute)
            const ushort* kf = kfp + (size_t)(t + 1) * 64 * CC;
            #pragma unroll
            for (int kb = 0; kb < 8; kb++) kr[vb ^ 1][kb] = *(const short8*)(kf + kb * 32);
            const int k0 = (t + 1) * 64;
            #pragma unroll
            for (int j = 0; j < 8; j++) {
                int ch = s_ch0 + j * 16 + s_chl;
                GLDS(Vg + (size_t)ch * HW + k0 + s_kh * 32 + s_kc,
                     &Vbuf[vb ^ 1][s_kh][s_ch0 + j * 16][0]);
            }
        }
        // ---- QK^T: S[64 q][16 keys of this wave], exp, scatter to Pbuf ----
        #pragma unroll
        for (int qt = 0; qt < 4; qt++) {
            float4_t s = (float4_t)(0.f);
            #pragma unroll
            for (int kb = 0; kb < 8; kb++)
                s = __builtin_amdgcn_mfma_f32_16x16x32_bf16(aq[qt][kb], kr[vb][kb], s, 0, 0, 0);
            #pragma unroll
            for (int r = 0; r < 4; r++)
                Pbuf[qt * 16 + quad * 4 + r][w * 16 + nidx] = f2b(exp2f(s[r] * SC));
        }
        __syncthreads();                                  // B2: P complete
        // ---- PV: o[ch(64 of wave)][q(64)] += V * P ----
        short8 Pb[4][2], Va[4][2];
        #pragma unroll
        for (int qt = 0; qt < 4; qt++)
            #pragma unroll
            for (int kh = 0; kh < 2; kh++)
                Pb[qt][kh] = *(const short8*)(&Pbuf[qt * 16 + nidx][kh * 32 + quad * 8]);
        #pragma unroll
        for (int ct = 0; ct < 4; ct++)
            #pragma unroll
            for (int kh = 0; kh < 2; kh++)
                Va[ct][kh] = *(const short8*)(&Vbuf[vb][kh][w * 64 + ct * 16 + nidx][quad * 8]);
        #pragma unroll
        for (int kh = 0; kh < 2; kh++)                    // row-sum partials: qt == w slice
            lacc = __builtin_amdgcn_mfma_f32_16x16x32_bf16(ones8, Pb[w][kh], lacc, 0, 0, 0);
        #pragma unroll
        for (int ct = 0; ct < 4; ct++)
            #pragma unroll
            for (int qt = 0; qt < 4; qt++)
                #pragma unroll
                for (int kh = 0; kh < 2; kh++)
                    o[ct][qt] = __builtin_amdgcn_mfma_f32_16x16x32_bf16(Va[ct][kh], Pb[qt][kh], o[ct][qt], 0, 0, 0);
    }
    // ---- epilogue: share l, normalize, store (coalesced via LDS round-trip) ----
    if (quad == 0) Lbuf[w * 16 + nidx] = lacc[0];         // l[q = w*16+nidx]
    __syncthreads();
    float linv[4];
    #pragma unroll
    for (int qt = 0; qt < 4; qt++) linv[qt] = 1.0f / Lbuf[qt * 16 + nidx];
    ushort* Obf = (ushort*)&Vbuf[0][0][0][0];             // alias: [64][256], staging dead
    #pragma unroll
    for (int ct = 0; ct < 4; ct++)
        #pragma unroll
        for (int qt = 0; qt < 4; qt++) {
            short4_t pk;
            #pragma unroll
            for (int r = 0; r < 4; r++) pk[r] = (short)f2b(o[ct][qt][r] * linv[qt]);
            *(short4_t*)(&Obf[(size_t)(qt * 16 + nidx) * 256 + w * 64 + ct * 16 + quad * 4]) = pk;
        }
    __syncthreads();
    ushort* dst = fT + (seq0 + p0) * CC;
    #pragma unroll
    for (int i = 0; i < 8; i++) {
        int idx = i * 256 + tid;
        *(short8*)(dst + (size_t)idx * 8) = *(const short8*)(Obf + idx * 8);
    }
}

// ---- kernel 4: out[n][co][p] = x + b[co] + sum_k W[co][k]*fT[p][k] ----
__global__ __launch_bounds__(256) void k_final(const unsigned short* __restrict__ Wc,
                                               const float* __restrict__ bc,
                                               const unsigned short* __restrict__ fT,
                                               const float* __restrict__ x,
                                               float* __restrict__ out) {
    int w = threadIdx.x >> 6, lane = threadIdx.x & 63;
    int nidx = lane & 15, quad = lane >> 4;
    int n = blockIdx.z;
    int co0 = blockIdx.y * 64 + w * 16;
    int p0 = blockIdx.x * 64;
    float4_t acc[4];
    #pragma unroll
    for (int i = 0; i < 4; i++) acc[i] = (float4_t)(0.f);
    const unsigned short* arow = Wc + (size_t)(co0 + nidx) * CC + quad * 8;
    const unsigned short* brow = fT + ((size_t)n * HW + p0 + nidx) * CC + quad * 8;
    for (int ks = 0; ks < 8; ks++) {
        short8 a = *(const short8*)(arow + ks * 32);
        #pragma unroll
        for (int pb = 0; pb < 4; pb++) {
            short8 bb = *(const short8*)(brow + (size_t)pb * 16 * CC + ks * 32);
            acc[pb] = __builtin_amdgcn_mfma_f32_16x16x32_bf16(a, bb, acc[pb], 0, 0, 0);
        }
    }
    #pragma unroll
    for (int pb = 0; pb < 4; pb++) {
        #pragma unroll
        for (int r = 0; r < 4; r++) {
            int co = co0 + quad * 4 + r;
            size_t idx = ((size_t)n * CC + co) * HW + p0 + pb * 16 + nidx;
            out[idx] = x[idx] + bc[co] + acc[pb][r];
        }
    }
}

extern "C" void kernel_launch(void* const* d_in, const int* in_sizes, int n_in,
                              void* d_out, int out_size, void* d_ws, size_t ws_size,
                              hipStream_t stream) {
    const float* x       = (const float*)d_in[0];
    const float* theta_w = (const float*)d_in[1];
    const float* theta_b = (const float*)d_in[2];
    const float* phi_w   = (const float*)d_in[3];
    const float* phi_b   = (const float*)d_in[4];
    const float* conv1_w = (const float*)d_in[5];
    const float* conv1_b = (const float*)d_in[6];
    float* out = (float*)d_out;

    const size_t SEQ = (size_t)NBATCH * HW;       // 16384
    unsigned short* XT  = (unsigned short*)d_ws;  // [SEQ][256]
    unsigned short* gb  = XT  + SEQ * CC;         // [N][256][4096]
    unsigned short* thT = gb  + SEQ * CC;         // [SEQ][256]
    unsigned short* phT = thT + SEQ * CC;         // [SEQ][256]
    unsigned short* fT  = phT + SEQ * CC;         // [SEQ][256]
    unsigned short* Wbt = fT  + SEQ * CC;
    unsigned short* Wbp = Wbt + 65536;
    unsigned short* Wbc = Wbp + 65536;

    k_prep<<<dim3(64, 4, 4), 256, 0, stream>>>(x, theta_w, phi_w, conv1_w, XT, gb, Wbt, Wbp, Wbc);
    k_proj<<<dim3(256, 2), 256, 0, stream>>>(XT, Wbt, Wbp, theta_b, phi_b, thT, phT);
    k_attn<<<dim3(256), 256, 0, stream>>>(thT, phT, gb, fT);
    k_final<<<dim3(64, 4, 4), 256, 0, stream>>>(Wbc, conv1_b, fT, x, out);
}

// Round 4
// 265.489 us; speedup vs baseline: 3.3770x; 3.3770x over previous
//
#include <hip/hip_runtime.h>
#include <hip/hip_bf16.h>

typedef __attribute__((ext_vector_type(8))) short short8;
typedef __attribute__((ext_vector_type(4))) short short4_t;
typedef __attribute__((ext_vector_type(4))) float float4_t;
typedef unsigned short ushort;

#define HW 4096
#define CC 256
#define NBATCH 4

static __device__ __forceinline__ unsigned short f2b(float f) {
    union { float f; unsigned u; } v; v.f = f;
    unsigned r = v.u + 0x7FFF + ((v.u >> 16) & 1);   // RNE
    return (unsigned short)(r >> 16);
}

// ---- kernel 1: x[n][c][p] -> XT[n][p][c] (bf16) and gb[n][c][p] (bf16),
//      with fused fp32->bf16 weight conversion (first 768 flat blocks). ----
__global__ __launch_bounds__(256) void k_prep(const float* __restrict__ x,
                                              const float* __restrict__ tw,
                                              const float* __restrict__ pw,
                                              const float* __restrict__ cw,
                                              unsigned short* __restrict__ XT,
                                              unsigned short* __restrict__ gb,
                                              unsigned short* __restrict__ Wbt,
                                              unsigned short* __restrict__ Wbp,
                                              unsigned short* __restrict__ Wbc) {
    __shared__ float T[64][65];
    int fb = blockIdx.x + 64 * (blockIdx.y + 4 * blockIdx.z);
    if (fb < 768) {            // 768*256 = 196608 = 3 x 256x256 weights
        int i = fb * 256 + threadIdx.x;
        int sel = i >> 16, off = i & 65535;
        const float* s = sel == 0 ? tw : (sel == 1 ? pw : cw);
        unsigned short* d = sel == 0 ? Wbt : (sel == 1 ? Wbp : Wbc);
        d[off] = f2b(s[off]);
    }
    int n = blockIdx.z, c0 = blockIdx.y * 64, p0 = blockIdx.x * 64;
    int t = threadIdx.x;
    int pl = t & 63, rg = t >> 6;
    const float* xp = x + ((size_t)n * CC + c0) * HW + p0;
    #pragma unroll
    for (int i = 0; i < 16; i++) {
        int cl = rg * 16 + i;
        float v = xp[(size_t)cl * HW + pl];
        T[cl][pl] = v;
        gb[((size_t)n * CC + c0 + cl) * HW + p0 + pl] = f2b(v);
    }
    __syncthreads();
    int cl = t & 63, pg = t >> 6;
    unsigned short* xt = XT + ((size_t)n * HW + p0) * CC + c0;
    #pragma unroll
    for (int i = 0; i < 16; i++) {
        int plw = pg * 16 + i;
        xt[(size_t)plw * CC + cl] = f2b(T[cl][plw]);
    }
}

// ---- kernel 2: projection GEMM  outT[p][co] = sum_ci XT[p][ci]*W[co][ci] + b[co] ----
__global__ __launch_bounds__(256) void k_proj(const unsigned short* __restrict__ XT,
                                              const unsigned short* __restrict__ Wt,
                                              const unsigned short* __restrict__ Wp,
                                              const float* __restrict__ bt,
                                              const float* __restrict__ bp,
                                              unsigned short* __restrict__ outT_t,
                                              unsigned short* __restrict__ outT_p) {
    const unsigned short* W; const float* b; unsigned short* outT;
    if (blockIdx.y == 0) { W = Wt; b = bt; outT = outT_t; }
    else                 { W = Wp; b = bp; outT = outT_p; }
    int w = threadIdx.x >> 6, lane = threadIdx.x & 63;
    int nidx = lane & 15, quad = lane >> 4;
    size_t row0 = (size_t)blockIdx.x * 64 + w * 16;
    float4_t acc[16];
    #pragma unroll
    for (int i = 0; i < 16; i++) acc[i] = (float4_t)(0.f);
    const unsigned short* arow = XT + (row0 + nidx) * CC + quad * 8;
    for (int ks = 0; ks < 8; ks++) {
        short8 a = *(const short8*)(arow + ks * 32);
        #pragma unroll
        for (int cb = 0; cb < 16; cb++) {
            short8 bb = *(const short8*)(W + (size_t)(cb * 16 + nidx) * CC + ks * 32 + quad * 8);
            acc[cb] = __builtin_amdgcn_mfma_f32_16x16x32_bf16(a, bb, acc[cb], 0, 0, 0);
        }
    }
    #pragma unroll
    for (int cb = 0; cb < 16; cb++) {
        int co = cb * 16 + nidx;
        float bias = b[co];
        #pragma unroll
        for (int r = 0; r < 4; r++) {
            size_t prow = row0 + quad * 4 + r;
            outT[prow * CC + co] = f2b(acc[cb][r] + bias);
        }
    }
}

// ---- kernel 3: flash attention, no-max softmax, no K/V LDS staging.
// Block = 64 q, 4 waves, KT=64 keys/tile, 64 tiles.
// QK^T role-swapped: A = K (wave's 16 keys, direct global b128), B = theta
//   (persistent regs) -> S^T[key][q]. exp -> P relayed through tiny LDS buffer
//   in FRAGMENT-MAJOR layout (reads are base+lane*16 streams, conflict-free).
// PV: A = V (wave's 64 ch, direct global b128), B = P-frags. All register
//   arrays statically indexed (round-3 spill bug: runtime-indexed reg arrays).
__global__ __launch_bounds__(256, 1) __attribute__((amdgpu_waves_per_eu(1)))
void k_attn(const unsigned short* __restrict__ thetaT,
            const unsigned short* __restrict__ phiT,
            const unsigned short* __restrict__ gb,
            unsigned short* __restrict__ fT) {
    __shared__ __align__(16) ushort Pbuf[2][8][64][8];   // [buf][frag(qt*2+kst)][lane][8] = 16 KB
    __shared__ __align__(16) ushort Obf[64][264];        // epilogue transpose, 33 KB
    __shared__ float Lbuf[4][64];

    const int tid = threadIdx.x;
    const int w = tid >> 6, lane = tid & 63;
    const int nidx = lane & 15, quad = lane >> 4;
    const int nb = (blockIdx.x & 7) >> 1;
    const int tile = ((blockIdx.x >> 3) << 1) | (blockIdx.x & 1);
    const int p0 = tile * 64;
    const size_t seq0 = (size_t)nb * HW;
    const ushort* Kg = phiT + seq0 * CC;                 // [4096][256]
    const ushort* Vg = gb + (size_t)nb * CC * HW;        // [256][4096]

    // persistent theta B-frags: th[qt][kb] : B[ch=quad*8+j][q=qt*16+nidx]
    short8 th[4][8];
    #pragma unroll
    for (int qt = 0; qt < 4; qt++) {
        const ushort* qrow = thetaT + (seq0 + p0 + qt * 16 + nidx) * CC + quad * 8;
        #pragma unroll
        for (int kb = 0; kb < 8; kb++) th[qt][kb] = *(const short8*)(qrow + kb * 32);
    }

    float4_t o[4][4];
    #pragma unroll
    for (int i = 0; i < 4; i++)
        #pragma unroll
        for (int j = 0; j < 4; j++) o[i][j] = (float4_t)(0.f);
    float lrow[4] = {0.f, 0.f, 0.f, 0.f};

    const ushort* kbase = Kg + (size_t)(w * 16 + nidx) * CC + quad * 8;
    const float SC = 0.0625f * 1.44269504088896f;        // /sqrt(256) * log2(e)

    auto loadK = [&](short8 (&kr)[8], int t) {
        const ushort* p = kbase + (size_t)t * 64 * CC;
        #pragma unroll
        for (int kb = 0; kb < 8; kb++) kr[kb] = *(const short8*)(p + kb * 32);
    };
    auto loadV = [&](short8 (&vr)[8], int t) {
        #pragma unroll
        for (int ct = 0; ct < 4; ct++)
            #pragma unroll
            for (int kst = 0; kst < 2; kst++)
                vr[ct * 2 + kst] = *(const short8*)(Vg + (size_t)(w * 64 + ct * 16 + nidx) * HW
                                                    + t * 64 + kst * 32 + quad * 8);
    };
    // P write target: frag (qt, kst=w>>1), cell lane = ((w&1)*2+(quad>>1))*16+nidx,
    // ushort offset (quad&1)*4  (keys w*16+quad*4+r land at within-frag k' = (w&1)*16+quad*4+r)
    const int pfrag_k = w >> 1;
    const int pcell = ((w & 1) * 2 + (quad >> 1)) * 16 + nidx;
    const int poff = (quad & 1) * 4;

    auto body = [&](const short8 (&kr)[8], const short8 (&vr)[8], int t) {
        const int buf = t & 1;
        // ---- QK^T: S^T[16 keys of wave][64 q], 4 independent acc chains ----
        float4_t s0 = (float4_t)(0.f), s1 = (float4_t)(0.f);
        float4_t s2 = (float4_t)(0.f), s3 = (float4_t)(0.f);
        #pragma unroll
        for (int kb = 0; kb < 8; kb++) {
            s0 = __builtin_amdgcn_mfma_f32_16x16x32_bf16(kr[kb], th[0][kb], s0, 0, 0, 0);
            s1 = __builtin_amdgcn_mfma_f32_16x16x32_bf16(kr[kb], th[1][kb], s1, 0, 0, 0);
            s2 = __builtin_amdgcn_mfma_f32_16x16x32_bf16(kr[kb], th[2][kb], s2, 0, 0, 0);
            s3 = __builtin_amdgcn_mfma_f32_16x16x32_bf16(kr[kb], th[3][kb], s3, 0, 0, 0);
        }
        // ---- exp, row-sum partials, pack to P relay (fragment-major) ----
        {
            float e0 = exp2f(s0[0] * SC), e1 = exp2f(s0[1] * SC);
            float e2 = exp2f(s0[2] * SC), e3 = exp2f(s0[3] * SC);
            lrow[0] += e0 + e1 + e2 + e3;
            short4_t pk = { (short)f2b(e0), (short)f2b(e1), (short)f2b(e2), (short)f2b(e3) };
            *(short4_t*)(&Pbuf[buf][0 * 2 + pfrag_k][pcell][poff]) = pk;
        }
        {
            float e0 = exp2f(s1[0] * SC), e1 = exp2f(s1[1] * SC);
            float e2 = exp2f(s1[2] * SC), e3 = exp2f(s1[3] * SC);
            lrow[1] += e0 + e1 + e2 + e3;
            short4_t pk = { (short)f2b(e0), (short)f2b(e1), (short)f2b(e2), (short)f2b(e3) };
            *(short4_t*)(&Pbuf[buf][1 * 2 + pfrag_k][pcell][poff]) = pk;
        }
        {
            float e0 = exp2f(s2[0] * SC), e1 = exp2f(s2[1] * SC);
            float e2 = exp2f(s2[2] * SC), e3 = exp2f(s2[3] * SC);
            lrow[2] += e0 + e1 + e2 + e3;
            short4_t pk = { (short)f2b(e0), (short)f2b(e1), (short)f2b(e2), (short)f2b(e3) };
            *(short4_t*)(&Pbuf[buf][2 * 2 + pfrag_k][pcell][poff]) = pk;
        }
        {
            float e0 = exp2f(s3[0] * SC), e1 = exp2f(s3[1] * SC);
            float e2 = exp2f(s3[2] * SC), e3 = exp2f(s3[3] * SC);
            lrow[3] += e0 + e1 + e2 + e3;
            short4_t pk = { (short)f2b(e0), (short)f2b(e1), (short)f2b(e2), (short)f2b(e3) };
            *(short4_t*)(&Pbuf[buf][3 * 2 + pfrag_k][pcell][poff]) = pk;
        }
        __syncthreads();                                  // P(t) complete
        // ---- PV: o[ch 64 of wave][q 64] += V * P, stream B-frag reads ----
        short8 pf[8];
        #pragma unroll
        for (int f = 0; f < 8; f++)
            pf[f] = *(const short8*)(&Pbuf[buf][f][lane][0]);
        #pragma unroll
        for (int ct = 0; ct < 4; ct++)
            #pragma unroll
            for (int qt = 0; qt < 4; qt++)
                #pragma unroll
                for (int kst = 0; kst < 2; kst++)
                    o[ct][qt] = __builtin_amdgcn_mfma_f32_16x16x32_bf16(
                        vr[ct * 2 + kst], pf[qt * 2 + kst], o[ct][qt], 0, 0, 0);
    };

    short8 kA[8], kB[8], vA[8], vB[8];
    loadK(kA, 0); loadV(vA, 0);
    #pragma unroll 1
    for (int tt = 0; tt < 32; tt++) {
        const int t0 = tt * 2;
        const int tn1 = t0 + 1;
        const int tn2 = t0 + 2 < 64 ? t0 + 2 : 63;
        loadK(kB, tn1); loadV(vB, tn1);                   // prefetch odd tile
        body(kA, vA, t0);
        loadK(kA, tn2); loadV(vA, tn2);                   // prefetch next even tile
        body(kB, vB, tn1);
    }

    // ---- epilogue: reduce l across quads + waves, normalize, store ----
    #pragma unroll
    for (int qt = 0; qt < 4; qt++) {
        float v = lrow[qt];
        v += __shfl_xor(v, 16);
        v += __shfl_xor(v, 32);
        if (quad == 0) Lbuf[w][qt * 16 + nidx] = v;
    }
    __syncthreads();
    float linv[4];
    #pragma unroll
    for (int qt = 0; qt < 4; qt++) {
        int q = qt * 16 + nidx;
        linv[qt] = 1.0f / (Lbuf[0][q] + Lbuf[1][q] + Lbuf[2][q] + Lbuf[3][q]);
    }
    // lane holds O[ch = w*64+ct*16+quad*4+r][q = qt*16+nidx]
    #pragma unroll
    for (int ct = 0; ct < 4; ct++)
        #pragma unroll
        for (int qt = 0; qt < 4; qt++) {
            short4_t pk;
            #pragma unroll
            for (int r = 0; r < 4; r++) pk[r] = (short)f2b(o[ct][qt][r] * linv[qt]);
            *(short4_t*)(&Obf[qt * 16 + nidx][w * 64 + ct * 16 + quad * 4]) = pk;
        }
    __syncthreads();
    ushort* dst = fT + (seq0 + p0) * CC;
    #pragma unroll
    for (int i = 0; i < 8; i++) {
        int c = i * 256 + tid;
        int q = c >> 5, cc = (c & 31) * 8;
        *(short8*)(dst + (size_t)q * CC + cc) = *(const short8*)(&Obf[q][cc]);
    }
}

// ---- kernel 4: out[n][co][p] = x + b[co] + sum_k W[co][k]*fT[p][k] ----
__global__ __launch_bounds__(256) void k_final(const unsigned short* __restrict__ Wc,
                                               const float* __restrict__ bc,
                                               const unsigned short* __restrict__ fT,
                                               const float* __restrict__ x,
                                               float* __restrict__ out) {
    int w = threadIdx.x >> 6, lane = threadIdx.x & 63;
    int nidx = lane & 15, quad = lane >> 4;
    int n = blockIdx.z;
    int co0 = blockIdx.y * 64 + w * 16;
    int p0 = blockIdx.x * 64;
    float4_t acc[4];
    #pragma unroll
    for (int i = 0; i < 4; i++) acc[i] = (float4_t)(0.f);
    const unsigned short* arow = Wc + (size_t)(co0 + nidx) * CC + quad * 8;
    const unsigned short* brow = fT + ((size_t)n * HW + p0 + nidx) * CC + quad * 8;
    for (int ks = 0; ks < 8; ks++) {
        short8 a = *(const short8*)(arow + ks * 32);
        #pragma unroll
        for (int pb = 0; pb < 4; pb++) {
            short8 bb = *(const short8*)(brow + (size_t)pb * 16 * CC + ks * 32);
            acc[pb] = __builtin_amdgcn_mfma_f32_16x16x32_bf16(a, bb, acc[pb], 0, 0, 0);
        }
    }
    #pragma unroll
    for (int pb = 0; pb < 4; pb++) {
        #pragma unroll
        for (int r = 0; r < 4; r++) {
            int co = co0 + quad * 4 + r;
            size_t idx = ((size_t)n * CC + co) * HW + p0 + pb * 16 + nidx;
            out[idx] = x[idx] + bc[co] + acc[pb][r];
        }
    }
}

extern "C" void kernel_launch(void* const* d_in, const int* in_sizes, int n_in,
                              void* d_out, int out_size, void* d_ws, size_t ws_size,
                              hipStream_t stream) {
    const float* x       = (const float*)d_in[0];
    const float* theta_w = (const float*)d_in[1];
    const float* theta_b = (const float*)d_in[2];
    const float* phi_w   = (const float*)d_in[3];
    const float* phi_b   = (const float*)d_in[4];
    const float* conv1_w = (const float*)d_in[5];
    const float* conv1_b = (const float*)d_in[6];
    float* out = (float*)d_out;

    const size_t SEQ = (size_t)NBATCH * HW;       // 16384
    unsigned short* XT  = (unsigned short*)d_ws;  // [SEQ][256]
    unsigned short* gb  = XT  + SEQ * CC;         // [N][256][4096]
    unsigned short* thT = gb  + SEQ * CC;         // [SEQ][256]
    unsigned short* phT = thT + SEQ * CC;         // [SEQ][256]
    unsigned short* fT  = phT + SEQ * CC;         // [SEQ][256]
    unsigned short* Wbt = fT  + SEQ * CC;
    unsigned short* Wbp = Wbt + 65536;
    unsigned short* Wbc = Wbp + 65536;

    k_prep<<<dim3(64, 4, 4), 256, 0, stream>>>(x, theta_w, phi_w, conv1_w, XT, gb, Wbt, Wbp, Wbc);
    k_proj<<<dim3(256, 2), 256, 0, stream>>>(XT, Wbt, Wbp, theta_b, phi_b, thT, phT);
    k_attn<<<dim3(256), 256, 0, stream>>>(thT, phT, gb, fT);
    k_final<<<dim3(64, 4, 4), 256, 0, stream>>>(Wbc, conv1_b, fT, x, out);
}